// Round 4
// baseline (7656.508 us; speedup 1.0000x reference)
//
#include <hip/hip_runtime.h>

typedef __bf16 bf16;
typedef __bf16 bf16x8 __attribute__((ext_vector_type(8)));
typedef float f32x4 __attribute__((ext_vector_type(4)));

#define T_LEN 512
#define BATCH 64
#define HID 256
#define LDA 520   // padded K-stride (bf16 elems)
#define ZLD 68    // padded fp32 stride for z tile

// workspace layout (~1.0 MB)
#define CTRL_BYTES 4096
#define H1_OFF CTRL_BYTES
#define HBUF_BYTES (2 * 3 * BATCH * HID * 2)     // dir x 3-slot x B x H x 2B
#define H2_OFF (H1_OFF + HBUF_BYTES)
#define LOG_OFF (H2_OFF + HBUF_BYTES)
#define LOG_BYTES (T_LEN * BATCH * 5 * 4)
#define ZERO_BYTES (LOG_OFF + LOG_BYTES)

// LDS layout
#define SMEM_A 66560
#define SMEM_Z 17408
#define SMEM_C 4096
#define SMEM_TAIL 576
#define SMEM_BYTES (SMEM_A + SMEM_Z + SMEM_C + SMEM_TAIL)

#define HSLOT_U32 (BATCH * HID / 2)   // 8192 u32 per slot

__device__ inline uint4 cvt8(const float4* s) {
    float4 a = s[0], b = s[1];
    union { uint4 u; bf16 h[8]; } r;
    r.h[0] = (bf16)a.x; r.h[1] = (bf16)a.y; r.h[2] = (bf16)a.z; r.h[3] = (bf16)a.w;
    r.h[4] = (bf16)b.x; r.h[5] = (bf16)b.y; r.h[6] = (bf16)b.z; r.h[7] = (bf16)b.w;
    return r.u;
}

__global__ void __launch_bounds__(256, 1)
lstm_kernel(const int* __restrict__ tokens,
            const float* __restrict__ embed,
            const float* __restrict__ W1f, const float* __restrict__ U1f, const float* __restrict__ b1f,
            const float* __restrict__ W2f, const float* __restrict__ U2f, const float* __restrict__ b2f,
            const float* __restrict__ W1b, const float* __restrict__ U1b, const float* __restrict__ b1b,
            const float* __restrict__ W2b, const float* __restrict__ U2b, const float* __restrict__ b2b,
            const float* __restrict__ dW,
            char* __restrict__ ws)
{
    extern __shared__ char smem[];
    bf16*  Abuf  = (bf16*)smem;
    float* zLds  = (float*)(smem + SMEM_A);
    float* cLds  = (float*)(smem + SMEM_A + SMEM_Z);
    float* bLds  = (float*)(smem + SMEM_A + SMEM_Z + SMEM_C);
    float* dwLds = bLds + 64;

    const int tid = threadIdx.x;
    const int wg  = blockIdx.x;
    const int dir = wg >> 5, layer = (wg >> 4) & 1, sub = wg & 15;

    const float *Wp, *Up, *bp;
    if (dir == 0) { if (layer == 0) { Wp=W1f; Up=U1f; bp=b1f; } else { Wp=W2f; Up=U2f; bp=b2f; } }
    else          { if (layer == 0) { Wp=W1b; Up=U1b; bp=b1b; } else { Wp=W2b; Up=U2b; bp=b2b; } }

    // ---- stage this WG's 64 gate-columns of [W;U] transposed into Abuf as bf16 ----
    {
        for (int it = 0; it < 32; ++it) {
            int idx = it * 256 + tid;
            int k = idx >> 4, q4 = idx & 15;
            int g = q4 >> 2, u0 = (q4 & 3) * 4;
            const float* src = (k < 256) ? (Wp + (size_t)k * 1024 + g * 256 + sub * 16 + u0)
                                         : (Up + (size_t)(k - 256) * 1024 + g * 256 + sub * 16 + u0);
            float4 v = *(const float4*)src;
            int c0 = g * 16 + u0;
            Abuf[(c0 + 0) * LDA + k] = (bf16)v.x;
            Abuf[(c0 + 1) * LDA + k] = (bf16)v.y;
            Abuf[(c0 + 2) * LDA + k] = (bf16)v.z;
            Abuf[(c0 + 3) * LDA + k] = (bf16)v.w;
        }
        if (tid < 64) {
            int g = tid >> 4, u = tid & 15;
            bLds[tid] = bp[g * 256 + sub * 16 + u];
        }
        if (tid < 80) {
            int u = tid / 5, c = tid % 5;
            dwLds[tid] = dW[(size_t)(dir * 256 + sub * 16 + u) * 5 + c];
        }
        for (int i = tid; i < 1024; i += 256) cLds[i] = 0.f;
    }
    __syncthreads();

    // ---- pin B fragments: wave covers a 32x32 quadrant of the 64x64 z tile ----
    const int wave = tid >> 6, lane = tid & 63, quad = lane >> 4, ln = lane & 15;
    const int mrow0 = (wave >> 1) * 32, ncol0 = (wave & 1) * 32;
    bf16x8 bfrag[2][16];
#pragma unroll
    for (int nt = 0; nt < 2; ++nt)
#pragma unroll
        for (int kt = 0; kt < 16; ++kt)
            bfrag[nt][kt] = *(const bf16x8*)&Abuf[(ncol0 + nt * 16 + ln) * LDA + kt * 32 + quad * 8];
    __syncthreads();

    unsigned* h1buf = (unsigned*)(ws + H1_OFF) + (size_t)dir * 3 * HSLOT_U32;
    unsigned* h2buf = (unsigned*)(ws + H2_OFF) + (size_t)dir * 3 * HSLOT_U32;
    unsigned* hOwn  = (layer == 0) ? h1buf : h2buf;
    float* logits   = (float*)(ws + LOG_OFF);
    unsigned* ctrOwn   = (unsigned*)ws + (dir * 2 + layer) * 32;       // 128 B apart
    unsigned* ctrOther = (unsigned*)ws + (dir * 2 + (1 - layer)) * 32;

    for (int s = 0; s < T_LEN; ++s) {
        // ---- dataflow waits (no fences, no L2 maintenance) ----
        if (tid == 0) {
            unsigned needOwn = (unsigned)s * 16u;
            unsigned needOther = (layer == 0)
                ? ((s >= 3) ? (unsigned)(s - 2) * 16u : 0u)   // 3-slot anti-overwrite throttle
                : (unsigned)(s + 1) * 16u;                    // x = h1 of step s must be complete
            while (__hip_atomic_load(ctrOwn, __ATOMIC_RELAXED, __HIP_MEMORY_SCOPE_AGENT) < needOwn)
                __builtin_amdgcn_s_sleep(1);
            while (__hip_atomic_load(ctrOther, __ATOMIC_RELAXED, __HIP_MEMORY_SCOPE_AGENT) < needOther)
                __builtin_amdgcn_s_sleep(1);
        }
        __syncthreads();
        asm volatile("" ::: "memory");

        // ---- build A = [x | h] in LDS ----
        {
            const int b = tid >> 2, q = tid & 3;
            if (layer == 0) {
                const int tt = dir ? (T_LEN - 1 - s) : s;
                const int tok = tokens[b * T_LEN + tt];
                const float4* src = (const float4*)(embed + (size_t)tok * HID + q * 64);
                uint4* dstx = (uint4*)&Abuf[b * LDA + q * 64];
#pragma unroll
                for (int j = 0; j < 8; ++j) dstx[j] = cvt8(src + j * 2);
            } else {
                unsigned* src = h1buf + (size_t)((s + 1) % 3) * HSLOT_U32 + b * 128 + q * 32;
                unsigned* dstx = (unsigned*)&Abuf[b * LDA + q * 64];
#pragma unroll
                for (int j = 0; j < 32; ++j)
                    dstx[j] = __hip_atomic_load(src + j, __ATOMIC_RELAXED, __HIP_MEMORY_SCOPE_AGENT);
            }
            unsigned* hsrc = hOwn + (size_t)(s % 3) * HSLOT_U32 + b * 128 + q * 32;
            unsigned* dsth = (unsigned*)&Abuf[b * LDA + 256 + q * 64];
#pragma unroll
            for (int j = 0; j < 32; ++j)
                dsth[j] = __hip_atomic_load(hsrc + j, __ATOMIC_RELAXED, __HIP_MEMORY_SCOPE_AGENT);
        }
        __syncthreads();

        // ---- GEMM: z[64x64] = A[64x512] @ Wt^T ----
        f32x4 acc[2][2];
#pragma unroll
        for (int mi = 0; mi < 2; ++mi)
#pragma unroll
            for (int ni = 0; ni < 2; ++ni) acc[mi][ni] = (f32x4)(0.0f);
#pragma unroll
        for (int kt = 0; kt < 16; ++kt) {
            bf16x8 a0 = *(const bf16x8*)&Abuf[(mrow0 + ln) * LDA + kt * 32 + quad * 8];
            bf16x8 a1 = *(const bf16x8*)&Abuf[(mrow0 + 16 + ln) * LDA + kt * 32 + quad * 8];
            acc[0][0] = __builtin_amdgcn_mfma_f32_16x16x32_bf16(a0, bfrag[0][kt], acc[0][0], 0, 0, 0);
            acc[0][1] = __builtin_amdgcn_mfma_f32_16x16x32_bf16(a0, bfrag[1][kt], acc[0][1], 0, 0, 0);
            acc[1][0] = __builtin_amdgcn_mfma_f32_16x16x32_bf16(a1, bfrag[0][kt], acc[1][0], 0, 0, 0);
            acc[1][1] = __builtin_amdgcn_mfma_f32_16x16x32_bf16(a1, bfrag[1][kt], acc[1][1], 0, 0, 0);
        }
#pragma unroll
        for (int mi = 0; mi < 2; ++mi)
#pragma unroll
            for (int ni = 0; ni < 2; ++ni) {
                int row = mrow0 + mi * 16 + quad * 4;
                int col = ncol0 + ni * 16 + ln;
#pragma unroll
                for (int r = 0; r < 4; ++r)
                    zLds[(row + r) * ZLD + col] = acc[mi][ni][r];
            }
        __syncthreads();

        // ---- gates + h store (coherent u32) + fused dense partial ----
        unsigned* hdst = hOwn + (size_t)((s + 1) % 3) * HSLOT_U32;
#pragma unroll
        for (int r = 0; r < 2; ++r) {
            int idx2 = r * 256 + tid;             // [0,512) = b*8 + up
            int b = idx2 >> 3, up = idx2 & 7, u0 = up * 2;
            float hv[2];
#pragma unroll
            for (int e = 0; e < 2; ++e) {
                int u = u0 + e;
                float zi = zLds[b * ZLD + u]      + bLds[u];
                float zf = zLds[b * ZLD + 16 + u] + bLds[16 + u];
                float zg = zLds[b * ZLD + 32 + u] + bLds[32 + u];
                float zo = zLds[b * ZLD + 48 + u] + bLds[48 + u];
                float ig = 1.f / (1.f + __expf(-zi));
                float fg = 1.f / (1.f + __expf(-zf));
                float gg = 1.f - 2.f / (__expf(2.f * zg) + 1.f);
                float og = 1.f / (1.f + __expf(-zo));
                float cn = fg * cLds[b * 16 + u] + ig * gg;
                cLds[b * 16 + u] = cn;
                hv[e] = og * (1.f - 2.f / (__expf(2.f * cn) + 1.f));
            }
            union { unsigned w; bf16 h[2]; } pk;
            pk.h[0] = (bf16)hv[0]; pk.h[1] = (bf16)hv[1];
            __hip_atomic_store(hdst + b * 128 + sub * 8 + up, pk.w,
                               __ATOMIC_RELAXED, __HIP_MEMORY_SCOPE_AGENT);
            if (layer == 1) {
                const int tp = dir ? (T_LEN - 1 - s) : s;
                float p0 = hv[0] * dwLds[u0 * 5 + 0] + hv[1] * dwLds[(u0 + 1) * 5 + 0];
                float p1 = hv[0] * dwLds[u0 * 5 + 1] + hv[1] * dwLds[(u0 + 1) * 5 + 1];
                float p2 = hv[0] * dwLds[u0 * 5 + 2] + hv[1] * dwLds[(u0 + 1) * 5 + 2];
                float p3 = hv[0] * dwLds[u0 * 5 + 3] + hv[1] * dwLds[(u0 + 1) * 5 + 3];
                float p4 = hv[0] * dwLds[u0 * 5 + 4] + hv[1] * dwLds[(u0 + 1) * 5 + 4];
#pragma unroll
                for (int m = 1; m < 8; m <<= 1) {
                    p0 += __shfl_xor(p0, m);
                    p1 += __shfl_xor(p1, m);
                    p2 += __shfl_xor(p2, m);
                    p3 += __shfl_xor(p3, m);
                    p4 += __shfl_xor(p4, m);
                }
                if (up == 0) {
                    float* lp = &logits[((size_t)tp * BATCH + b) * 5];
                    atomicAdd(lp + 0, p0);
                    atomicAdd(lp + 1, p1);
                    atomicAdd(lp + 2, p2);
                    atomicAdd(lp + 3, p3);
                    atomicAdd(lp + 4, p4);
                }
            }
        }

        // ---- completion publish: drain own stores, then count ----
        asm volatile("s_waitcnt vmcnt(0)" ::: "memory");
        __syncthreads();
        if (tid == 0)
            __hip_atomic_fetch_add(ctrOwn, 1u, __ATOMIC_RELAXED, __HIP_MEMORY_SCOPE_AGENT);
    }
}

__global__ void __launch_bounds__(256)
softmax_kernel(const char* __restrict__ ws, const float* __restrict__ dB, float* __restrict__ out)
{
    const int gid = blockIdx.x * 256 + threadIdx.x;
    const int b = gid & 63, t = gid >> 6;
    const float* lp = (const float*)(ws + LOG_OFF) + ((size_t)t * BATCH + b) * 5;
    float l[5];
#pragma unroll
    for (int c = 0; c < 5; ++c) l[c] = lp[c] + dB[c];
    float m = l[0];
#pragma unroll
    for (int c = 1; c < 5; ++c) m = fmaxf(m, l[c]);
    float e[5], ssum = 0.f;
#pragma unroll
    for (int c = 0; c < 5; ++c) { e[c] = __expf(l[c] - m); ssum += e[c]; }
    float inv = 1.f / ssum;
    float* o = out + ((size_t)b * T_LEN + t) * 5;
#pragma unroll
    for (int c = 0; c < 5; ++c) o[c] = e[c] * inv;
}

extern "C" void kernel_launch(void* const* d_in, const int* in_sizes, int n_in,
                              void* d_out, int out_size, void* d_ws, size_t ws_size,
                              hipStream_t stream)
{
    const int*   tokens = (const int*)d_in[0];
    const float* embed  = (const float*)d_in[1];
    const float* W1f = (const float*)d_in[2],  *U1f = (const float*)d_in[3],  *b1f = (const float*)d_in[4];
    const float* W2f = (const float*)d_in[5],  *U2f = (const float*)d_in[6],  *b2f = (const float*)d_in[7];
    const float* W1b = (const float*)d_in[8],  *U1b = (const float*)d_in[9],  *b1b = (const float*)d_in[10];
    const float* W2b = (const float*)d_in[11], *U2b = (const float*)d_in[12], *b2b = (const float*)d_in[13];
    const float* dW  = (const float*)d_in[14], *dB  = (const float*)d_in[15];

    hipFuncSetAttribute(reinterpret_cast<const void*>(lstm_kernel),
                        hipFuncAttributeMaxDynamicSharedMemorySize, SMEM_BYTES);
    hipMemsetAsync(d_ws, 0, ZERO_BYTES, stream);
    lstm_kernel<<<dim3(64), dim3(256), SMEM_BYTES, stream>>>(
        tokens, embed, W1f, U1f, b1f, W2f, U2f, b2f,
        W1b, U1b, b1b, W2b, U2b, b2b, dW, (char*)d_ws);
    softmax_kernel<<<dim3(128), dim3(256), 0, stream>>>((const char*)d_ws, dB, (float*)d_out);
}

// Round 5
// 6887.305 us; speedup vs baseline: 1.1117x; 1.1117x over previous
//
#include <hip/hip_runtime.h>

typedef __bf16 bf16;
typedef __bf16 bf16x8 __attribute__((ext_vector_type(8)));
typedef float f32x4 __attribute__((ext_vector_type(4)));

#define T_LEN 512
#define BATCH 64
#define HID 256
#define LDA 520   // padded K-stride (bf16 elems)
#define ZLD 68    // padded fp32 stride for z tile

// workspace layout (~1.0 MB)
#define CTRL_BYTES 4096
#define H1_OFF CTRL_BYTES
#define HBUF_BYTES (2 * 3 * BATCH * HID * 2)     // dir x 3-slot x B x H x 2B
#define H2_OFF (H1_OFF + HBUF_BYTES)
#define LOG_OFF (H2_OFF + HBUF_BYTES)
#define LOG_BYTES (T_LEN * BATCH * 5 * 4)
#define ZERO_BYTES (LOG_OFF + LOG_BYTES)

// LDS layout
#define SMEM_A 66560
#define SMEM_Z 17408
#define SMEM_C 4096
#define SMEM_TAIL 576
#define SMEM_BYTES (SMEM_A + SMEM_Z + SMEM_C + SMEM_TAIL)

#define HSLOT_U32 (BATCH * HID / 2)   // 8192 u32 per slot

__device__ inline uint4 cvt8(const float4* s) {
    float4 a = s[0], b = s[1];
    union { uint4 u; bf16 h[8]; } r;
    r.h[0] = (bf16)a.x; r.h[1] = (bf16)a.y; r.h[2] = (bf16)a.z; r.h[3] = (bf16)a.w;
    r.h[4] = (bf16)b.x; r.h[5] = (bf16)b.y; r.h[6] = (bf16)b.z; r.h[7] = (bf16)b.w;
    return r.u;
}

__global__ void __launch_bounds__(256, 1)
lstm_kernel(const int* __restrict__ tokens,
            const float* __restrict__ embed,
            const float* __restrict__ W1f, const float* __restrict__ U1f, const float* __restrict__ b1f,
            const float* __restrict__ W2f, const float* __restrict__ U2f, const float* __restrict__ b2f,
            const float* __restrict__ W1b, const float* __restrict__ U1b, const float* __restrict__ b1b,
            const float* __restrict__ W2b, const float* __restrict__ U2b, const float* __restrict__ b2b,
            const float* __restrict__ dW,
            char* __restrict__ ws)
{
    extern __shared__ char smem[];
    bf16*  Abuf  = (bf16*)smem;
    float* zLds  = (float*)(smem + SMEM_A);
    float* cLds  = (float*)(smem + SMEM_A + SMEM_Z);
    float* bLds  = (float*)(smem + SMEM_A + SMEM_Z + SMEM_C);
    float* dwLds = bLds + 64;

    const int tid = threadIdx.x;
    const int wg  = blockIdx.x;
    const int dir = wg >> 5, layer = (wg >> 4) & 1, sub = wg & 15;

    const float *Wp, *Up, *bp;
    if (dir == 0) { if (layer == 0) { Wp=W1f; Up=U1f; bp=b1f; } else { Wp=W2f; Up=U2f; bp=b2f; } }
    else          { if (layer == 0) { Wp=W1b; Up=U1b; bp=b1b; } else { Wp=W2b; Up=U2b; bp=b2b; } }

    // ---- stage this WG's 64 gate-columns of [W;U] transposed into Abuf as bf16 ----
    {
        for (int it = 0; it < 32; ++it) {
            int idx = it * 256 + tid;
            int k = idx >> 4, q4 = idx & 15;
            int g = q4 >> 2, u0 = (q4 & 3) * 4;
            const float* src = (k < 256) ? (Wp + (size_t)k * 1024 + g * 256 + sub * 16 + u0)
                                         : (Up + (size_t)(k - 256) * 1024 + g * 256 + sub * 16 + u0);
            float4 v = *(const float4*)src;
            int c0 = g * 16 + u0;
            Abuf[(c0 + 0) * LDA + k] = (bf16)v.x;
            Abuf[(c0 + 1) * LDA + k] = (bf16)v.y;
            Abuf[(c0 + 2) * LDA + k] = (bf16)v.z;
            Abuf[(c0 + 3) * LDA + k] = (bf16)v.w;
        }
        if (tid < 64) {
            int g = tid >> 4, u = tid & 15;
            bLds[tid] = bp[g * 256 + sub * 16 + u];
        }
        if (tid < 80) {
            int u = tid / 5, c = tid % 5;
            dwLds[tid] = dW[(size_t)(dir * 256 + sub * 16 + u) * 5 + c];
        }
        for (int i = tid; i < 1024; i += 256) cLds[i] = 0.f;
    }
    __syncthreads();

    // ---- pin B fragments: wave covers a 32x32 quadrant of the 64x64 z tile ----
    const int wave = tid >> 6, lane = tid & 63, quad = lane >> 4, ln = lane & 15;
    const int mrow0 = (wave >> 1) * 32, ncol0 = (wave & 1) * 32;
    bf16x8 bfrag[2][16];
#pragma unroll
    for (int nt = 0; nt < 2; ++nt)
#pragma unroll
        for (int kt = 0; kt < 16; ++kt)
            bfrag[nt][kt] = *(const bf16x8*)&Abuf[(ncol0 + nt * 16 + ln) * LDA + kt * 32 + quad * 8];
    __syncthreads();

    unsigned* h1buf = (unsigned*)(ws + H1_OFF) + (size_t)dir * 3 * HSLOT_U32;
    unsigned* h2buf = (unsigned*)(ws + H2_OFF) + (size_t)dir * 3 * HSLOT_U32;
    unsigned* hOwn  = (layer == 0) ? h1buf : h2buf;
    float* logits   = (float*)(ws + LOG_OFF);
    unsigned* ctrOwn = (unsigned*)ws + (dir * 2 + layer) * 32;       // 128 B apart
    unsigned* ctrL1  = (unsigned*)ws + (dir * 2 + 0) * 32;
    unsigned* ctrL2  = (unsigned*)ws + (dir * 2 + 1) * 32;

    const int bA = tid >> 2, qA = tid & 3;   // A-build role: batch row, quarter

    // ---- embed/token software pipeline state (layer 0 only) ----
    float4 pf[16];
    int tokB = 0;
    if (layer == 0) {
        const int tt0 = dir ? (T_LEN - 1) : 0;
        int tokA = tokens[bA * T_LEN + tt0];
        const float4* src = (const float4*)(embed + (size_t)tokA * HID + qA * 64);
#pragma unroll
        for (int j = 0; j < 16; ++j) pf[j] = src[j];
        const int tt1 = dir ? (T_LEN - 2) : 1;
        tokB = tokens[bA * T_LEN + tt1];
    }

    for (int s = 0; s < T_LEN; ++s) {
        // ---- dataflow waits (tid0 spins; others park at barrier) ----
        if (tid == 0) {
            unsigned needOwn = (unsigned)s * 16u;
            while (__hip_atomic_load(ctrOwn, __ATOMIC_RELAXED, __HIP_MEMORY_SCOPE_AGENT) < needOwn) {}
            if (layer == 0 && s >= 3) {
                unsigned needT = (unsigned)(s - 2) * 16u;   // 3-slot anti-overwrite throttle
                while (__hip_atomic_load(ctrL2, __ATOMIC_RELAXED, __HIP_MEMORY_SCOPE_AGENT) < needT) {}
            }
        }
        __syncthreads();

        // ---- batched coherent loads into registers ----
        unsigned hreg[32];
        {
            unsigned* hsrc = hOwn + (size_t)(s % 3) * HSLOT_U32 + bA * 128 + qA * 32;
#pragma unroll
            for (int j = 0; j < 32; ++j)
                hreg[j] = __hip_atomic_load(hsrc + j, __ATOMIC_RELAXED, __HIP_MEMORY_SCOPE_AGENT);
        }
        if (layer == 0) {
            // x part comes from prefetched embed regs
            uint4* dstx = (uint4*)&Abuf[bA * LDA + qA * 64];
#pragma unroll
            for (int j = 0; j < 8; ++j) dstx[j] = cvt8(&pf[2 * j]);
        } else {
            // wait for L1 to finish step s, then batched x loads
            if (tid == 0) {
                unsigned needX = (unsigned)(s + 1) * 16u;
                while (__hip_atomic_load(ctrL1, __ATOMIC_RELAXED, __HIP_MEMORY_SCOPE_AGENT) < needX) {}
            }
            __syncthreads();          // own-h loads stay in flight during the spin
            unsigned xreg[32];
            unsigned* xsrc = h1buf + (size_t)((s + 1) % 3) * HSLOT_U32 + bA * 128 + qA * 32;
#pragma unroll
            for (int j = 0; j < 32; ++j)
                xreg[j] = __hip_atomic_load(xsrc + j, __ATOMIC_RELAXED, __HIP_MEMORY_SCOPE_AGENT);
            unsigned* dstx = (unsigned*)&Abuf[bA * LDA + qA * 64];
#pragma unroll
            for (int j = 0; j < 32; ++j) dstx[j] = xreg[j];
        }
        {
            unsigned* dsth = (unsigned*)&Abuf[bA * LDA + 256 + qA * 64];
#pragma unroll
            for (int j = 0; j < 32; ++j) dsth[j] = hreg[j];
        }
        __syncthreads();

        // ---- prefetch embed for step s+1 (issues early; RT hidden under GEMM) ----
        if (layer == 0) {
            const float4* src = (const float4*)(embed + (size_t)tokB * HID + qA * 64);
#pragma unroll
            for (int j = 0; j < 16; ++j) pf[j] = src[j];
            const int sn2 = (s + 2 < T_LEN) ? s + 2 : T_LEN - 1;
            const int tt2 = dir ? (T_LEN - 1 - sn2) : sn2;
            tokB = tokens[bA * T_LEN + tt2];
        }

        // ---- GEMM: z[64x64] = A[64x512] @ Wt^T ----
        f32x4 acc[2][2];
#pragma unroll
        for (int mi = 0; mi < 2; ++mi)
#pragma unroll
            for (int ni = 0; ni < 2; ++ni) acc[mi][ni] = (f32x4)(0.0f);
#pragma unroll
        for (int kt = 0; kt < 16; ++kt) {
            bf16x8 a0 = *(const bf16x8*)&Abuf[(mrow0 + ln) * LDA + kt * 32 + quad * 8];
            bf16x8 a1 = *(const bf16x8*)&Abuf[(mrow0 + 16 + ln) * LDA + kt * 32 + quad * 8];
            acc[0][0] = __builtin_amdgcn_mfma_f32_16x16x32_bf16(a0, bfrag[0][kt], acc[0][0], 0, 0, 0);
            acc[0][1] = __builtin_amdgcn_mfma_f32_16x16x32_bf16(a0, bfrag[1][kt], acc[0][1], 0, 0, 0);
            acc[1][0] = __builtin_amdgcn_mfma_f32_16x16x32_bf16(a1, bfrag[0][kt], acc[1][0], 0, 0, 0);
            acc[1][1] = __builtin_amdgcn_mfma_f32_16x16x32_bf16(a1, bfrag[1][kt], acc[1][1], 0, 0, 0);
        }
#pragma unroll
        for (int mi = 0; mi < 2; ++mi)
#pragma unroll
            for (int ni = 0; ni < 2; ++ni) {
                int row = mrow0 + mi * 16 + quad * 4;
                int col = ncol0 + ni * 16 + ln;
#pragma unroll
                for (int r = 0; r < 4; ++r)
                    zLds[(row + r) * ZLD + col] = acc[mi][ni][r];
            }
        __syncthreads();

        // ---- gates + h store (coherent u32); logits deferred past publish ----
        unsigned* hdst = hOwn + (size_t)((s + 1) % 3) * HSLOT_U32;
        float pr[2][5];
#pragma unroll
        for (int r = 0; r < 2; ++r) {
            int idx2 = r * 256 + tid;             // [0,512) = b*8 + up
            int b = idx2 >> 3, up = idx2 & 7, u0 = up * 2;
            float hv[2];
#pragma unroll
            for (int e = 0; e < 2; ++e) {
                int u = u0 + e;
                float zi = zLds[b * ZLD + u]      + bLds[u];
                float zf = zLds[b * ZLD + 16 + u] + bLds[16 + u];
                float zg = zLds[b * ZLD + 32 + u] + bLds[32 + u];
                float zo = zLds[b * ZLD + 48 + u] + bLds[48 + u];
                float ig = 1.f / (1.f + __expf(-zi));
                float fg = 1.f / (1.f + __expf(-zf));
                float gg = 1.f - 2.f / (__expf(2.f * zg) + 1.f);
                float og = 1.f / (1.f + __expf(-zo));
                float cn = fg * cLds[b * 16 + u] + ig * gg;
                cLds[b * 16 + u] = cn;
                hv[e] = og * (1.f - 2.f / (__expf(2.f * cn) + 1.f));
            }
            union { unsigned w; bf16 h[2]; } pk;
            pk.h[0] = (bf16)hv[0]; pk.h[1] = (bf16)hv[1];
            __hip_atomic_store(hdst + b * 128 + sub * 8 + up, pk.w,
                               __ATOMIC_RELAXED, __HIP_MEMORY_SCOPE_AGENT);
            if (layer == 1) {
#pragma unroll
                for (int c = 0; c < 5; ++c)
                    pr[r][c] = hv[0] * dwLds[u0 * 5 + c] + hv[1] * dwLds[(u0 + 1) * 5 + c];
#pragma unroll
                for (int m = 1; m < 8; m <<= 1)
#pragma unroll
                    for (int c = 0; c < 5; ++c) pr[r][c] += __shfl_xor(pr[r][c], m);
            }
        }

        // ---- completion publish: drain h stores, then count ----
        asm volatile("s_waitcnt vmcnt(0)" ::: "memory");
        __syncthreads();
        if (tid == 0)
            __hip_atomic_fetch_add(ctrOwn, 1u, __ATOMIC_RELAXED, __HIP_MEMORY_SCOPE_AGENT);

        // ---- deferred logits accumulation (off the critical path) ----
        if (layer == 1) {
            const int tp = dir ? (T_LEN - 1 - s) : s;
#pragma unroll
            for (int r = 0; r < 2; ++r) {
                int idx2 = r * 256 + tid;
                int b = idx2 >> 3, up = idx2 & 7;
                if (up == 0) {
                    float* lp = &logits[((size_t)tp * BATCH + b) * 5];
#pragma unroll
                    for (int c = 0; c < 5; ++c) atomicAdd(lp + c, pr[r][c]);
                }
            }
        }
    }
}

__global__ void __launch_bounds__(256)
softmax_kernel(const char* __restrict__ ws, const float* __restrict__ dB, float* __restrict__ out)
{
    const int gid = blockIdx.x * 256 + threadIdx.x;
    const int b = gid & 63, t = gid >> 6;
    const float* lp = (const float*)(ws + LOG_OFF) + ((size_t)t * BATCH + b) * 5;
    float l[5];
#pragma unroll
    for (int c = 0; c < 5; ++c) l[c] = lp[c] + dB[c];
    float m = l[0];
#pragma unroll
    for (int c = 1; c < 5; ++c) m = fmaxf(m, l[c]);
    float e[5], ssum = 0.f;
#pragma unroll
    for (int c = 0; c < 5; ++c) { e[c] = __expf(l[c] - m); ssum += e[c]; }
    float inv = 1.f / ssum;
    float* o = out + ((size_t)b * T_LEN + t) * 5;
#pragma unroll
    for (int c = 0; c < 5; ++c) o[c] = e[c] * inv;
}

extern "C" void kernel_launch(void* const* d_in, const int* in_sizes, int n_in,
                              void* d_out, int out_size, void* d_ws, size_t ws_size,
                              hipStream_t stream)
{
    const int*   tokens = (const int*)d_in[0];
    const float* embed  = (const float*)d_in[1];
    const float* W1f = (const float*)d_in[2],  *U1f = (const float*)d_in[3],  *b1f = (const float*)d_in[4];
    const float* W2f = (const float*)d_in[5],  *U2f = (const float*)d_in[6],  *b2f = (const float*)d_in[7];
    const float* W1b = (const float*)d_in[8],  *U1b = (const float*)d_in[9],  *b1b = (const float*)d_in[10];
    const float* W2b = (const float*)d_in[11], *U2b = (const float*)d_in[12], *b2b = (const float*)d_in[13];
    const float* dW  = (const float*)d_in[14], *dB  = (const float*)d_in[15];

    hipFuncSetAttribute(reinterpret_cast<const void*>(lstm_kernel),
                        hipFuncAttributeMaxDynamicSharedMemorySize, SMEM_BYTES);
    hipMemsetAsync(d_ws, 0, ZERO_BYTES, stream);
    lstm_kernel<<<dim3(64), dim3(256), SMEM_BYTES, stream>>>(
        tokens, embed, W1f, U1f, b1f, W2f, U2f, b2f,
        W1b, U1b, b1b, W2b, U2b, b2b, dW, (char*)d_ws);
    softmax_kernel<<<dim3(128), dim3(256), 0, stream>>>((const char*)d_ws, dB, (float*)d_out);
}

// Round 6
// 3103.400 us; speedup vs baseline: 2.4671x; 2.2193x over previous
//
#include <hip/hip_runtime.h>

typedef __bf16 bf16;
typedef __bf16 bf16x8 __attribute__((ext_vector_type(8)));
typedef float f32x4 __attribute__((ext_vector_type(4)));
typedef unsigned long long u64;

#define T_LEN 512
#define BATCH 64
#define HID 256
#define LDA 520   // padded K-stride (bf16 elems); row = 1040 B, 16B-aligned
#define ZLD 68    // padded fp32 stride for z tile

// workspace layout (~1.0 MB)
#define CTRL_BYTES 4096
#define H1_OFF CTRL_BYTES
#define HSLOT_U64 4096                           // 64 b x 256 hid x 2B / 8
#define HBUF_BYTES (2 * 3 * HSLOT_U64 * 8)       // dir x 3-slot
#define H2_OFF (H1_OFF + HBUF_BYTES)
#define LOG_OFF (H2_OFF + HBUF_BYTES)
#define LOG_BYTES (T_LEN * BATCH * 5 * 4)
#define ZERO_BYTES (LOG_OFF + LOG_BYTES)

// LDS layout
#define SMEM_A 66560
#define SMEM_Z 17408
#define SMEM_C 4096
#define SMEM_TAIL 576
#define SMEM_BYTES (SMEM_A + SMEM_Z + SMEM_C + SMEM_TAIL)

__device__ inline uint4 cvt8(const float4* s) {
    float4 a = s[0], b = s[1];
    union { uint4 u; bf16 h[8]; } r;
    r.h[0] = (bf16)a.x; r.h[1] = (bf16)a.y; r.h[2] = (bf16)a.z; r.h[3] = (bf16)a.w;
    r.h[4] = (bf16)b.x; r.h[5] = (bf16)b.y; r.h[6] = (bf16)b.z; r.h[7] = (bf16)b.w;
    return r.u;
}

__global__ void __launch_bounds__(256, 1)
lstm_kernel(const int* __restrict__ tokens,
            const float* __restrict__ embed,
            const float* __restrict__ W1f, const float* __restrict__ U1f, const float* __restrict__ b1f,
            const float* __restrict__ W2f, const float* __restrict__ U2f, const float* __restrict__ b2f,
            const float* __restrict__ W1b, const float* __restrict__ U1b, const float* __restrict__ b1b,
            const float* __restrict__ W2b, const float* __restrict__ U2b, const float* __restrict__ b2b,
            const float* __restrict__ dW,
            char* __restrict__ ws)
{
    extern __shared__ char smem[];
    bf16*  Abuf  = (bf16*)smem;
    float* zLds  = (float*)(smem + SMEM_A);
    float* cLds  = (float*)(smem + SMEM_A + SMEM_Z);
    float* bLds  = (float*)(smem + SMEM_A + SMEM_Z + SMEM_C);
    float* dwLds = bLds + 64;

    const int tid = threadIdx.x;
    const int wg  = blockIdx.x;
    // XCD co-location: 16 WGs of one (dir,layer) land on blockIdx == {c, c+4} mod 8
    const int dir = wg & 1, layer = (wg >> 1) & 1, sub = wg >> 2;

    const float *Wp, *Up, *bp;
    if (dir == 0) { if (layer == 0) { Wp=W1f; Up=U1f; bp=b1f; } else { Wp=W2f; Up=U2f; bp=b2f; } }
    else          { if (layer == 0) { Wp=W1b; Up=U1b; bp=b1b; } else { Wp=W2b; Up=U2b; bp=b2b; } }

    // ---- stage this WG's 64 gate-columns of [W;U] transposed into Abuf as bf16 ----
    {
        for (int it = 0; it < 32; ++it) {
            int idx = it * 256 + tid;
            int k = idx >> 4, q4 = idx & 15;
            int g = q4 >> 2, u0 = (q4 & 3) * 4;
            const float* src = (k < 256) ? (Wp + (size_t)k * 1024 + g * 256 + sub * 16 + u0)
                                         : (Up + (size_t)(k - 256) * 1024 + g * 256 + sub * 16 + u0);
            float4 v = *(const float4*)src;
            int c0 = g * 16 + u0;
            Abuf[(c0 + 0) * LDA + k] = (bf16)v.x;
            Abuf[(c0 + 1) * LDA + k] = (bf16)v.y;
            Abuf[(c0 + 2) * LDA + k] = (bf16)v.z;
            Abuf[(c0 + 3) * LDA + k] = (bf16)v.w;
        }
        if (tid < 64) {
            int g = tid >> 4, u = tid & 15;
            bLds[tid] = bp[g * 256 + sub * 16 + u];
        }
        if (tid < 80) {
            int u = tid / 5, c = tid % 5;
            dwLds[tid] = dW[(size_t)(dir * 256 + sub * 16 + u) * 5 + c];
        }
        for (int i = tid; i < 1024; i += 256) cLds[i] = 0.f;
    }
    __syncthreads();

    // ---- pin B fragments: wave covers a 32x32 quadrant of the 64x64 z tile ----
    const int wave = tid >> 6, lane = tid & 63, quad = lane >> 4, ln = lane & 15;
    const int mrow0 = (wave >> 1) * 32, ncol0 = (wave & 1) * 32;
    bf16x8 bfrag[2][16];
#pragma unroll
    for (int nt = 0; nt < 2; ++nt)
#pragma unroll
        for (int kt = 0; kt < 16; ++kt)
            bfrag[nt][kt] = *(const bf16x8*)&Abuf[(ncol0 + nt * 16 + ln) * LDA + kt * 32 + quad * 8];
    __syncthreads();

    u64* h1buf = (u64*)(ws + H1_OFF) + (size_t)dir * 3 * HSLOT_U64;
    u64* h2buf = (u64*)(ws + H2_OFF) + (size_t)dir * 3 * HSLOT_U64;
    u64* hOwn  = (layer == 0) ? h1buf : h2buf;
    float* logits   = (float*)(ws + LOG_OFF);
    unsigned* ctrOwn = (unsigned*)ws + (dir * 2 + layer) * 32;       // 128 B apart
    unsigned* ctrL1  = (unsigned*)ws + (dir * 2 + 0) * 32;
    unsigned* ctrL2  = (unsigned*)ws + (dir * 2 + 1) * 32;

    const int bA = tid >> 2, qA = tid & 3;   // A-build / gates role

    // ---- embed/token software pipeline state (layer 0 only) ----
    float4 pf[16];
    int tokB = 0;
    if (layer == 0) {
        const int tt0 = dir ? (T_LEN - 1) : 0;
        int tokA = tokens[bA * T_LEN + tt0];
        const float4* src = (const float4*)(embed + (size_t)tokA * HID + qA * 64);
#pragma unroll
        for (int j = 0; j < 16; ++j) pf[j] = src[j];
        const int tt1 = dir ? (T_LEN - 2) : 1;
        tokB = tokens[bA * T_LEN + tt1];
    }

    for (int s = 0; s < T_LEN; ++s) {
        // ---- dataflow waits (tid0 spins; others park at barrier) ----
        if (tid == 0) {
            unsigned needOwn = (unsigned)s * 16u;
            while (__hip_atomic_load(ctrOwn, __ATOMIC_RELAXED, __HIP_MEMORY_SCOPE_AGENT) < needOwn) {}
            if (layer == 0 && s >= 3) {
                unsigned needT = (unsigned)(s - 2) * 16u;   // 3-slot anti-overwrite throttle
                while (__hip_atomic_load(ctrL2, __ATOMIC_RELAXED, __HIP_MEMORY_SCOPE_AGENT) < needT) {}
            }
        }
        __syncthreads();

        // ---- own h: 16 coalesced u64 coherent loads (k*256+tid) ----
        u64 hreg[16];
        {
            const u64* hsrc = hOwn + (size_t)(s % 3) * HSLOT_U64;
#pragma unroll
            for (int k = 0; k < 16; ++k)
                hreg[k] = __hip_atomic_load(hsrc + k * 256 + tid, __ATOMIC_RELAXED, __HIP_MEMORY_SCOPE_AGENT);
        }
        // ---- x part ----
        if (layer == 0) {
            uint4* dstx = (uint4*)&Abuf[bA * LDA + qA * 64];
#pragma unroll
            for (int j = 0; j < 8; ++j) dstx[j] = cvt8(&pf[2 * j]);
        } else {
            if (tid == 0) {
                unsigned needX = (unsigned)(s + 1) * 16u;
                while (__hip_atomic_load(ctrL1, __ATOMIC_RELAXED, __HIP_MEMORY_SCOPE_AGENT) < needX) {}
            }
            __syncthreads();          // own-h loads complete during the spin
            u64 xreg[16];
            const u64* xsrc = h1buf + (size_t)((s + 1) % 3) * HSLOT_U64;
#pragma unroll
            for (int k = 0; k < 16; ++k)
                xreg[k] = __hip_atomic_load(xsrc + k * 256 + tid, __ATOMIC_RELAXED, __HIP_MEMORY_SCOPE_AGENT);
            // scatter to LDS: u64 (k*256+tid) -> row (tid>>2), x-col k*16 + (tid&3)*4
#pragma unroll
            for (int k = 0; k < 16; ++k)
                *(u64*)&Abuf[bA * LDA + k * 16 + qA * 4] = xreg[k];
        }
        // own-h scatter: row (tid>>2), h-col 256 + k*16 + (tid&3)*4  (natural hid order)
#pragma unroll
        for (int k = 0; k < 16; ++k)
            *(u64*)&Abuf[bA * LDA + 256 + k * 16 + qA * 4] = hreg[k];
        __syncthreads();

        // ---- prefetch embed for step s+1 (RT hidden under GEMM) ----
        if (layer == 0) {
            const float4* src = (const float4*)(embed + (size_t)tokB * HID + qA * 64);
#pragma unroll
            for (int j = 0; j < 16; ++j) pf[j] = src[j];
            const int sn2 = (s + 2 < T_LEN) ? s + 2 : T_LEN - 1;
            const int tt2 = dir ? (T_LEN - 1 - sn2) : sn2;
            tokB = tokens[bA * T_LEN + tt2];
        }

        // ---- GEMM: z[64x64] = A[64x512] @ Wt^T ----
        f32x4 acc[2][2];
#pragma unroll
        for (int mi = 0; mi < 2; ++mi)
#pragma unroll
            for (int ni = 0; ni < 2; ++ni) acc[mi][ni] = (f32x4)(0.0f);
#pragma unroll
        for (int kt = 0; kt < 16; ++kt) {
            bf16x8 a0 = *(const bf16x8*)&Abuf[(mrow0 + ln) * LDA + kt * 32 + quad * 8];
            bf16x8 a1 = *(const bf16x8*)&Abuf[(mrow0 + 16 + ln) * LDA + kt * 32 + quad * 8];
            acc[0][0] = __builtin_amdgcn_mfma_f32_16x16x32_bf16(a0, bfrag[0][kt], acc[0][0], 0, 0, 0);
            acc[0][1] = __builtin_amdgcn_mfma_f32_16x16x32_bf16(a0, bfrag[1][kt], acc[0][1], 0, 0, 0);
            acc[1][0] = __builtin_amdgcn_mfma_f32_16x16x32_bf16(a1, bfrag[0][kt], acc[1][0], 0, 0, 0);
            acc[1][1] = __builtin_amdgcn_mfma_f32_16x16x32_bf16(a1, bfrag[1][kt], acc[1][1], 0, 0, 0);
        }
#pragma unroll
        for (int mi = 0; mi < 2; ++mi)
#pragma unroll
            for (int ni = 0; ni < 2; ++ni) {
                int row = mrow0 + mi * 16 + quad * 4;
                int col = ncol0 + ni * 16 + ln;
#pragma unroll
                for (int r = 0; r < 4; ++r)
                    zLds[(row + r) * ZLD + col] = acc[mi][ni][r];
            }
        __syncthreads();

        // ---- gates: thread = (b=tid>>2, u = (tid&3)*4 .. +3); one u64 coherent store ----
        u64* hdst = hOwn + (size_t)((s + 1) % 3) * HSLOT_U64;
        float hv[4];
        {
            const int b = bA, u0 = qA * 4;
#pragma unroll
            for (int e = 0; e < 4; ++e) {
                int u = u0 + e;
                float zi = zLds[b * ZLD + u]      + bLds[u];
                float zf = zLds[b * ZLD + 16 + u] + bLds[16 + u];
                float zg = zLds[b * ZLD + 32 + u] + bLds[32 + u];
                float zo = zLds[b * ZLD + 48 + u] + bLds[48 + u];
                float ig = 1.f / (1.f + __expf(-zi));
                float fg = 1.f / (1.f + __expf(-zf));
                float gg = 1.f - 2.f / (__expf(2.f * zg) + 1.f);
                float og = 1.f / (1.f + __expf(-zo));
                float cn = fg * cLds[b * 16 + u] + ig * gg;
                cLds[b * 16 + u] = cn;
                hv[e] = og * (1.f - 2.f / (__expf(2.f * cn) + 1.f));
            }
            union { u64 w; bf16 h[4]; } pk;
#pragma unroll
            for (int e = 0; e < 4; ++e) pk.h[e] = (bf16)hv[e];
            __hip_atomic_store(hdst + sub * 256 + tid, pk.w,
                               __ATOMIC_RELAXED, __HIP_MEMORY_SCOPE_AGENT);
        }
        float pr[5];
        if (layer == 1) {
#pragma unroll
            for (int c = 0; c < 5; ++c)
                pr[c] = hv[0] * dwLds[(qA * 4 + 0) * 5 + c] + hv[1] * dwLds[(qA * 4 + 1) * 5 + c]
                      + hv[2] * dwLds[(qA * 4 + 2) * 5 + c] + hv[3] * dwLds[(qA * 4 + 3) * 5 + c];
#pragma unroll
            for (int m = 1; m < 4; m <<= 1)
#pragma unroll
                for (int c = 0; c < 5; ++c) pr[c] += __shfl_xor(pr[c], m);
        }

        // ---- completion publish: drain h stores, then count ----
        asm volatile("s_waitcnt vmcnt(0)" ::: "memory");
        __syncthreads();
        if (tid == 0)
            __hip_atomic_fetch_add(ctrOwn, 1u, __ATOMIC_RELAXED, __HIP_MEMORY_SCOPE_AGENT);

        // ---- deferred logits accumulation (off the critical path) ----
        if (layer == 1 && qA == 0) {
            const int tp = dir ? (T_LEN - 1 - s) : s;
            float* lp = &logits[((size_t)tp * BATCH + bA) * 5];
#pragma unroll
            for (int c = 0; c < 5; ++c) atomicAdd(lp + c, pr[c]);
        }
    }
}

__global__ void __launch_bounds__(256)
softmax_kernel(const char* __restrict__ ws, const float* __restrict__ dB, float* __restrict__ out)
{
    const int gid = blockIdx.x * 256 + threadIdx.x;
    const int b = gid & 63, t = gid >> 6;
    const float* lp = (const float*)(ws + LOG_OFF) + ((size_t)t * BATCH + b) * 5;
    float l[5];
#pragma unroll
    for (int c = 0; c < 5; ++c) l[c] = lp[c] + dB[c];
    float m = l[0];
#pragma unroll
    for (int c = 1; c < 5; ++c) m = fmaxf(m, l[c]);
    float e[5], ssum = 0.f;
#pragma unroll
    for (int c = 0; c < 5; ++c) { e[c] = __expf(l[c] - m); ssum += e[c]; }
    float inv = 1.f / ssum;
    float* o = out + ((size_t)b * T_LEN + t) * 5;
#pragma unroll
    for (int c = 0; c < 5; ++c) o[c] = e[c] * inv;
}

extern "C" void kernel_launch(void* const* d_in, const int* in_sizes, int n_in,
                              void* d_out, int out_size, void* d_ws, size_t ws_size,
                              hipStream_t stream)
{
    const int*   tokens = (const int*)d_in[0];
    const float* embed  = (const float*)d_in[1];
    const float* W1f = (const float*)d_in[2],  *U1f = (const float*)d_in[3],  *b1f = (const float*)d_in[4];
    const float* W2f = (const float*)d_in[5],  *U2f = (const float*)d_in[6],  *b2f = (const float*)d_in[7];
    const float* W1b = (const float*)d_in[8],  *U1b = (const float*)d_in[9],  *b1b = (const float*)d_in[10];
    const float* W2b = (const float*)d_in[11], *U2b = (const float*)d_in[12], *b2b = (const float*)d_in[13];
    const float* dW  = (const float*)d_in[14], *dB  = (const float*)d_in[15];

    hipFuncSetAttribute(reinterpret_cast<const void*>(lstm_kernel),
                        hipFuncAttributeMaxDynamicSharedMemorySize, SMEM_BYTES);
    hipMemsetAsync(d_ws, 0, ZERO_BYTES, stream);
    lstm_kernel<<<dim3(64), dim3(256), SMEM_BYTES, stream>>>(
        tokens, embed, W1f, U1f, b1f, W2f, U2f, b2f,
        W1b, U1b, b1b, W2b, U2b, b2b, dW, (char*)d_ws);
    softmax_kernel<<<dim3(128), dim3(256), 0, stream>>>((const char*)d_ws, dB, (float*)d_out);
}